// Round 8
// baseline (296.619 us; speedup 1.0000x reference)
//
#include <hip/hip_runtime.h>
#include <hip/hip_bf16.h>

// ---------------------------------------------------------------------------
// GCN 2-layer forward, round 20 — FINAL DECOMPOSITION (intentional slowdown).
// = r17 EXACTLY, plus gemm2 x5 and agg64 x5 (both pure/idempotent, zero
//   side-effect counters -> risk-free duplication).
//   Ledger so far: agg128 = 27.9us (r18). buildchain+gemm2+agg64 = 62.35us
//   (r19, incl ~5 gaps). F(fixed) ~= 85us. Models say gemm2~5, agg64~13,
//   build~11 (sum 30) -> 2x off somewhere; this round locates it.
//   Read-out: S = (dur - 175.5 - ~8us gaps)/4 = gemm2+agg64;
//             build = 62.35 - S - 5*gap.
//   Pre-committed: S<=18 -> attack buildchain next; S>=30 -> aggs at BW
//   wall, one locality attempt then likely roofline (F dominates).
// History: r18 agg128=28us. r17/r16 store-coalescing NULL. r15 atomic-free
// build WIN. r13 atomic-scope NULL (TCC RMW throughput wall). r11 fusion BAD.
// ---------------------------------------------------------------------------

#define GCN_IN   128
#define GCN_H    128
#define GCN_OUT  64
#define CAP      64
#define OVF_CAP  32768
#define SPILL_CAP 65536
#define PASSA_BLOCKS 256
#define SEG_CAP  24          // per-(bucket,block) capacity; Poisson(8) tail ~0
#define SORT_CAP 4096        // max edges per passA block (strided split)

using short8 = __attribute__((ext_vector_type(8))) short;   // 8 bf16, 4 VGPRs
using f32x4  = __attribute__((ext_vector_type(4))) float;   // MFMA acc
using int4v  = __attribute__((ext_vector_type(4))) int;     // native vec4 int

__device__ __forceinline__ ushort f2bf(float f) {     // fp32 -> bf16 RNE
    uint b = __float_as_uint(f);
    b = (b + 0x7FFFu + ((b >> 16) & 1u)) >> 16;
    return (ushort)b;
}
__device__ __forceinline__ float bf2f_lo(uint u) { return __uint_as_float(u << 16); }
__device__ __forceinline__ float bf2f_hi(uint u) { return __uint_as_float(u & 0xFFFF0000u); }

// ---------------- fused: [0,PASSA) bucket sort || [PASSA,..) MFMA GEMM1 -----
__global__ __launch_bounds__(256) void k_fused1(
        const int* __restrict__ src, const int* __restrict__ dst,
        uint* __restrict__ seg, ushort* __restrict__ cntAB,
        int* __restrict__ spillcnt, uint* __restrict__ spill, int E,
        const float* __restrict__ A, const float* __restrict__ B,
        ushort* __restrict__ C, int M, int N) {
    __shared__ __align__(16) uint smemU[5760];     // 23040 B union
    const int tid = threadIdx.x;
    const int nb  = (N + 127) >> 7;                // buckets (391 @ N=50000)

    if (blockIdx.x < PASSA_BLOCKS) {
        uint* histL  = smemU;                      // [512]
        uint* scanEx = smemU + 512;                // [512]
        uint* hist2  = smemU + 1024;               // [512]
        uint* sorted = smemU + 1536;               // [SORT_CAP]
        uint* totalS = smemU + 1536 + SORT_CAP;    // [1]

        const int blk = blockIdx.x;
        const int stride4 = PASSA_BLOCKS * 256 * 4;
        for (int i = tid; i < 512; i += 256) { histL[i] = 0; hist2[i] = 0; }
        __syncthreads();

        // phase 1: histogram of this block's edges over buckets
        for (int e = (blk * 256 + tid) * 4; e < E; e += stride4) {
            int4v d4 = __builtin_nontemporal_load((const int4v*)(dst + e));
            #pragma unroll
            for (int k = 0; k < 4; ++k) atomicAdd(&histL[d4[k] >> 7], 1u);
        }
        __syncthreads();

        // phase 2: single-wave exclusive scan over 512 buckets
        if (tid < 64) {
            int base = tid * 8;
            uint loc[8];
            uint run = 0;
            #pragma unroll
            for (int j = 0; j < 8; ++j) { loc[j] = run; run += histL[base + j]; }
            uint inc = run;
            #pragma unroll
            for (int d = 1; d < 64; d <<= 1) {
                uint v = __shfl_up(inc, d, 64);
                if (tid >= d) inc += v;
            }
            uint exc = inc - run;
            #pragma unroll
            for (int j = 0; j < 8; ++j) scanEx[base + j] = exc + loc[j];
            if (tid == 63) totalS[0] = inc;        // block's edge count
        }
        __syncthreads();

        // per-(bucket,block) counts for passB
        for (int b = tid; b < nb; b += 256)
            cntAB[(size_t)b * PASSA_BLOCKS + blk] =
                (ushort)min((int)histL[b], SEG_CAP);

        // phase 3: re-read edges (L2-hot), rank-scatter into LDS
        for (int e = (blk * 256 + tid) * 4; e < E; e += stride4) {
            int4v d4 = __builtin_nontemporal_load((const int4v*)(dst + e));
            int4v s4 = __builtin_nontemporal_load((const int4v*)(src + e));
            #pragma unroll
            for (int k = 0; k < 4; ++k) {
                int d = d4[k];
                int b = d >> 7;
                uint r = atomicAdd(&hist2[b], 1u);
                sorted[scanEx[b] + r] = ((uint)d << 16) | (uint)s4[k];
            }
        }
        __syncthreads();

        // phase 4: linear write-out; bucket runs are consecutive dwords
        const int myE = (int)totalS[0];
        for (int i = tid; i < myE; i += 256) {
            uint pr = sorted[i];
            int b = (int)(pr >> 23);               // d>>7
            int gpos = i - (int)scanEx[b];
            if (gpos < SEG_CAP) {
                seg[((size_t)b * PASSA_BLOCKS + blk) * SEG_CAP + gpos] = pr;
            } else {                               // ~0.1 expected, graph-fixed
                int q = atomicAdd(spillcnt, 1);
                if (q < SPILL_CAP) spill[q] = pr;
            }
        }
        return;
    }

    // ---- MFMA GEMM1: 64 rows x 128 cols per block, BK=32 chunks ----
    ushort (*As)[40] = (ushort (*)[40])(smemU);           // 64x40 bf16, 5120B
    ushort (*Bs)[40] = (ushort (*)[40])(smemU + 1280);    // 128x40 bf16, 10240B
    const int g    = blockIdx.x - PASSA_BLOCKS;
    const int row0 = g * 64;
    const int w    = tid >> 6;
    const int lane = tid & 63;
    const int l15  = lane & 15;
    const int q8   = (lane >> 4) * 8;

    f32x4 acc[8];
    #pragma unroll
    for (int t = 0; t < 8; ++t) {
        acc[t][0] = 0.f; acc[t][1] = 0.f; acc[t][2] = 0.f; acc[t][3] = 0.f;
    }
    for (int kb = 0; kb < 128; kb += 32) {
        #pragma unroll
        for (int tt = 0; tt < 2; ++tt) {
            int f = tid * 4 + tt * 1024;
            int r = f >> 5;
            int k = f & 31;
            float4 v = make_float4(0.f, 0.f, 0.f, 0.f);
            int gr = row0 + r;
            if (gr < M) v = *(const float4*)(A + (size_t)gr * 128 + kb + k);
            ushort4 o;
            o.x = f2bf(v.x); o.y = f2bf(v.y); o.z = f2bf(v.z); o.w = f2bf(v.w);
            *(ushort4*)&As[r][k] = o;
        }
        #pragma unroll
        for (int tt = 0; tt < 4; ++tt) {
            int f = tid * 4 + tt * 1024;
            int k = f >> 7;
            int n = f & 127;
            float4 v = *(const float4*)(B + (size_t)(kb + k) * 128 + n);
            Bs[n + 0][k] = f2bf(v.x);
            Bs[n + 1][k] = f2bf(v.y);
            Bs[n + 2][k] = f2bf(v.z);
            Bs[n + 3][k] = f2bf(v.w);
        }
        __syncthreads();
        short8 a = *(const short8*)&As[16 * w + l15][q8];
        #pragma unroll
        for (int t = 0; t < 8; ++t) {
            short8 b = *(const short8*)&Bs[16 * t + l15][q8];
            acc[t] = __builtin_amdgcn_mfma_f32_16x16x32_bf16(a, b, acc[t], 0, 0, 0);
        }
        __syncthreads();
    }
    const int quad = lane >> 4;
    #pragma unroll
    for (int r = 0; r < 4; ++r) {
        int grow = row0 + 16 * w + quad * 4 + r;
        if (grow < M) {
            #pragma unroll
            for (int t = 0; t < 8; ++t) {
                __builtin_nontemporal_store(
                    f2bf(acc[t][r]), C + (size_t)grow * 128 + 16 * t + l15);
            }
        }
    }
}

// ---------------- passB: per-bucket slot/cnt build, LDS-staged window -------
__global__ __launch_bounds__(256) void k_passB(const uint* __restrict__ seg,
                                               const ushort* __restrict__ cntAB,
                                               const int* __restrict__ spillcnt,
                                               const uint* __restrict__ spill,
                                               int* __restrict__ cnt,
                                               ushort* __restrict__ slot,
                                               int* __restrict__ ovfcnt,
                                               int2* __restrict__ ovf, int N) {
    __shared__ int cntL[128];
    __shared__ __align__(16) ushort slotL[128 * CAP];   // 16KB window
    const int tid  = threadIdx.x;
    const int b    = blockIdx.x;
    const int base = b << 7;
    if (tid < 128) cntL[tid] = 0;
    __syncthreads();

    const int cs = (int)cntAB[(size_t)b * PASSA_BLOCKS + tid];
    const uint* sp = seg + ((size_t)b * PASSA_BLOCKS + tid) * SEG_CAP;
    for (int c4 = 0; c4 < SEG_CAP; c4 += 4) {
        if (c4 >= cs) break;
        uint4 v = *(const uint4*)(sp + c4);            // 16B-aligned (96B seg)
        const uint* vv = (const uint*)&v;
        #pragma unroll
        for (int k = 0; k < 4; ++k) {
            int idx = c4 + k;
            if (idx < cs) {
                uint pr = vv[k];
                int d = (int)(pr >> 16);
                int s = (int)(pr & 0xFFFFu);
                int pos = atomicAdd(&cntL[d - base], 1);   // LDS
                if (pos < CAP) {
                    slotL[(d - base) * CAP + pos] = (ushort)s;
                } else {                                   // degree > 64: ~never
                    int q = atomicAdd(ovfcnt, 1);
                    if (q < OVF_CAP) ovf[q] = make_int2(d, s);
                }
            }
        }
    }
    // spill drain (expected 0-2 entries total across the whole graph)
    const int spn = min(*spillcnt, SPILL_CAP);
    for (int t = tid; t < spn; t += 256) {
        uint pr = spill[t];
        int d = (int)(pr >> 16);
        if (d >= base && d < base + 128) {
            int s = (int)(pr & 0xFFFFu);
            int pos = atomicAdd(&cntL[d - base], 1);
            if (pos < CAP) {
                slotL[(d - base) * CAP + pos] = (ushort)s;
            } else {
                int q = atomicAdd(ovfcnt, 1);
                if (q < OVF_CAP) ovf[q] = make_int2(d, s);
            }
        }
    }
    __syncthreads();
    // cnt: sole owner, write directly (no memset needed)
    if (tid < 128) {
        int d = base + tid;
        if (d < N) cnt[d] = cntL[tid];
    }
    // slot window: dense uint4 write-out (unwritten entries = LDS garbage,
    // same class as harness poison; agg masks beyond degm).
    ushort* swin = slot + (size_t)base * CAP;
    const uint4* sl4 = (const uint4*)slotL;
    #pragma unroll
    for (int t = 0; t < 4; ++t) {
        int i = tid + t * 256;                     // uint4 index, row = i>>3
        if (base + (i >> 3) < N) ((uint4*)swin)[i] = sl4[i];
    }
}

// ---------------- agg layer 1: F=128, unscaled bf16 in, bf16 out, relu ------
__global__ __launch_bounds__(256) void k_agg128(const ushort* __restrict__ h,
                                                const int* __restrict__ cnt,
                                                const ushort* __restrict__ slot,
                                                const float* __restrict__ bias,
                                                const int* __restrict__ ovfcnt,
                                                const int2* __restrict__ ovf,
                                                ushort* __restrict__ out, int n) {
    int node = (blockIdx.x * 256 + threadIdx.x) >> 6;
    int lane = threadIdx.x & 63;
    if (node >= n) return;
    int deg = cnt[node];
    int degm = min(deg, CAP);
    float isd_i = rsqrtf((float)(deg + 1));
    int sidx = (int)__builtin_nontemporal_load(slot + (size_t)node * CAP + lane);
    bool valid = lane < degm;
    if (!valid) sidx = 0;
    float wl = valid ? rsqrtf((float)(cnt[sidx] + 1)) : 0.f;

    const int q = lane >> 4;          // 0..3
    const int i = lane & 15;          // 0..15
    const ushort* hp = h + 8 * i;     // 8 bf16 feats per lane

    float acc[8] = {};
    for (int j = 0; j < degm; j += 8) {          // 8 edges/iter, 2 gathers
        int j0 = j + q;
        int j1 = j + 4 + q;
        int   s0 = __shfl(sidx, j0);
        int   s1 = __shfl(sidx, j1);
        float w0 = __shfl(wl, j0);               // 0 beyond degm
        float w1 = __shfl(wl, j1);
        uint4 v0 = *(const uint4*)(hp + (size_t)s0 * 128);
        uint4 v1 = *(const uint4*)(hp + (size_t)s1 * 128);
        acc[0] += w0 * bf2f_lo(v0.x) + w1 * bf2f_lo(v1.x);
        acc[1] += w0 * bf2f_hi(v0.x) + w1 * bf2f_hi(v1.x);
        acc[2] += w0 * bf2f_lo(v0.y) + w1 * bf2f_lo(v1.y);
        acc[3] += w0 * bf2f_hi(v0.y) + w1 * bf2f_hi(v1.y);
        acc[4] += w0 * bf2f_lo(v0.z) + w1 * bf2f_lo(v1.z);
        acc[5] += w0 * bf2f_hi(v0.z) + w1 * bf2f_hi(v1.z);
        acc[6] += w0 * bf2f_lo(v0.w) + w1 * bf2f_lo(v1.w);
        acc[7] += w0 * bf2f_hi(v0.w) + w1 * bf2f_hi(v1.w);
    }
    int ovn = *ovfcnt;                            // ~always 0
    for (int t = 0; t < ovn; ++t) {
        int2 p = ovf[t];
        if (p.x == node && q == 0) {
            float w0 = rsqrtf((float)(cnt[p.y] + 1));
            uint4 v0 = *(const uint4*)(hp + (size_t)p.y * 128);
            acc[0] += w0 * bf2f_lo(v0.x); acc[1] += w0 * bf2f_hi(v0.x);
            acc[2] += w0 * bf2f_lo(v0.y); acc[3] += w0 * bf2f_hi(v0.y);
            acc[4] += w0 * bf2f_lo(v0.z); acc[5] += w0 * bf2f_hi(v0.z);
            acc[6] += w0 * bf2f_lo(v0.w); acc[7] += w0 * bf2f_hi(v0.w);
        }
    }
    #pragma unroll
    for (int k = 0; k < 8; ++k) {                 // fold quads
        acc[k] += __shfl_xor(acc[k], 16);
        acc[k] += __shfl_xor(acc[k], 32);
    }
    if (q == 0) {
        uint4 vs = *(const uint4*)(hp + (size_t)node * 128);  // self (unscaled)
        float4 ba = *(const float4*)(bias + 8 * i);
        float4 bb = *(const float4*)(bias + 8 * i + 4);
        float r0 = fmaxf((acc[0] + isd_i * bf2f_lo(vs.x)) * isd_i + ba.x, 0.f);
        float r1 = fmaxf((acc[1] + isd_i * bf2f_hi(vs.x)) * isd_i + ba.y, 0.f);
        float r2 = fmaxf((acc[2] + isd_i * bf2f_lo(vs.y)) * isd_i + ba.z, 0.f);
        float r3 = fmaxf((acc[3] + isd_i * bf2f_hi(vs.y)) * isd_i + ba.w, 0.f);
        float r4 = fmaxf((acc[4] + isd_i * bf2f_lo(vs.z)) * isd_i + bb.x, 0.f);
        float r5 = fmaxf((acc[5] + isd_i * bf2f_hi(vs.z)) * isd_i + bb.y, 0.f);
        float r6 = fmaxf((acc[6] + isd_i * bf2f_lo(vs.w)) * isd_i + bb.z, 0.f);
        float r7 = fmaxf((acc[7] + isd_i * bf2f_hi(vs.w)) * isd_i + bb.w, 0.f);
        uint4 o;
        o.x = (uint)f2bf(r0) | ((uint)f2bf(r1) << 16);
        o.y = (uint)f2bf(r2) | ((uint)f2bf(r3) << 16);
        o.z = (uint)f2bf(r4) | ((uint)f2bf(r5) << 16);
        o.w = (uint)f2bf(r6) | ((uint)f2bf(r7) << 16);
        *(uint4*)(out + (size_t)node * 128 + 8 * i) = o;
    }
}

// ---------------- MFMA GEMM2: h2[N][64] bf16 (isd-scaled) = h1 @ W2 ---------
__global__ __launch_bounds__(256) void k_gemm2(const ushort* __restrict__ A,
                                               const float* __restrict__ B,
                                               const int* __restrict__ cnt,
                                               ushort* __restrict__ C, int M) {
    __shared__ __align__(16) ushort As[64][136];   // [m][k] bf16
    __shared__ __align__(16) ushort Bs[64][136];   // [n][k] bf16 (W2^T)
    const int tid  = threadIdx.x;
    const int w    = tid >> 6;
    const int lane = tid & 63;
    const int l15  = lane & 15;
    const int q8   = (lane >> 4) * 8;
    const int row0 = blockIdx.x * 64;

    #pragma unroll
    for (int t = 0; t < 4; ++t) {
        int f = tid * 8 + t * 2048;
        int r = f >> 7;
        int k = f & 127;
        uint4 v = make_uint4(0u, 0u, 0u, 0u);
        int gr = row0 + r;
        if (gr < M) v = *(const uint4*)(A + (size_t)gr * 128 + k);
        *(uint4*)&As[r][k] = v;
    }
    #pragma unroll
    for (int t = 0; t < 8; ++t) {
        int f = tid * 4 + t * 1024;
        int k = f >> 6;
        int n = f & 63;
        float4 v = *(const float4*)(B + (size_t)k * 64 + n);
        Bs[n + 0][k] = f2bf(v.x);
        Bs[n + 1][k] = f2bf(v.y);
        Bs[n + 2][k] = f2bf(v.z);
        Bs[n + 3][k] = f2bf(v.w);
    }
    __syncthreads();

    f32x4 acc[4];
    #pragma unroll
    for (int t = 0; t < 4; ++t) {
        acc[t][0] = 0.f; acc[t][1] = 0.f; acc[t][2] = 0.f; acc[t][3] = 0.f;
    }
    #pragma unroll
    for (int kt = 0; kt < 4; ++kt) {
        short8 a = *(const short8*)&As[16 * w + l15][32 * kt + q8];
        #pragma unroll
        for (int t = 0; t < 4; ++t) {
            short8 b = *(const short8*)&Bs[16 * t + l15][32 * kt + q8];
            acc[t] = __builtin_amdgcn_mfma_f32_16x16x32_bf16(a, b, acc[t], 0, 0, 0);
        }
    }
    const int quad = lane >> 4;
    #pragma unroll
    for (int r = 0; r < 4; ++r) {
        int grow = row0 + 16 * w + quad * 4 + r;
        if (grow < M) {
            float ws = rsqrtf((float)(cnt[grow] + 1));   // pre-scale by isd_src
            #pragma unroll
            for (int t = 0; t < 4; ++t) {
                C[(size_t)grow * 64 + 16 * t + l15] = f2bf(ws * acc[t][r]);
            }
        }
    }
}

// ---------------- agg layer 2: F=64, prescaled bf16 in, fp32 out ------------
__global__ __launch_bounds__(256) void k_agg64(const ushort* __restrict__ h,
                                               const int* __restrict__ cnt,
                                               const ushort* __restrict__ slot,
                                               const float* __restrict__ bias,
                                               const int* __restrict__ ovfcnt,
                                               const int2* __restrict__ ovf,
                                               float* __restrict__ out, int n) {
    int node = (blockIdx.x * 256 + threadIdx.x) >> 6;
    int lane = threadIdx.x & 63;
    if (node >= n) return;
    int deg = cnt[node];
    int degm = min(deg, CAP);
    float isd_i = rsqrtf((float)(deg + 1));
    int sidx = (int)__builtin_nontemporal_load(slot + (size_t)node * CAP + lane);

    const int g = lane >> 3;          // 0..7
    const int i = lane & 7;           // 0..7
    const ushort* hp = h + 8 * i;

    float acc[8] = {};
    for (int j = 0; j < degm; j += 16) {         // 16 edges/iter, 2 gathers
        int j0 = j + g;
        int j1 = j + 8 + g;
        int   s0 = __shfl(sidx, j0);
        int   s1 = __shfl(sidx, j1);
        float w0 = (j0 < degm) ? 1.f : 0.f;
        float w1 = (j1 < degm) ? 1.f : 0.f;
        uint4 v0 = *(const uint4*)(hp + (size_t)s0 * 64);
        uint4 v1 = *(const uint4*)(hp + (size_t)s1 * 64);
        acc[0] += w0 * bf2f_lo(v0.x) + w1 * bf2f_lo(v1.x);
        acc[1] += w0 * bf2f_hi(v0.x) + w1 * bf2f_hi(v1.x);
        acc[2] += w0 * bf2f_lo(v0.y) + w1 * bf2f_lo(v1.y);
        acc[3] += w0 * bf2f_hi(v0.y) + w1 * bf2f_hi(v1.y);
        acc[4] += w0 * bf2f_lo(v0.z) + w1 * bf2f_lo(v1.z);
        acc[5] += w0 * bf2f_hi(v0.z) + w1 * bf2f_hi(v1.z);
        acc[6] += w0 * bf2f_lo(v0.w) + w1 * bf2f_lo(v1.w);
        acc[7] += w0 * bf2f_hi(v0.w) + w1 * bf2f_hi(v1.w);
    }
    int ovn = *ovfcnt;
    for (int t = 0; t < ovn; ++t) {
        int2 p = ovf[t];
        if (p.x == node && g == 0) {             // h2 rows prescaled by isd_s
            uint4 v0 = *(const uint4*)(hp + (size_t)p.y * 64);
            acc[0] += bf2f_lo(v0.x); acc[1] += bf2f_hi(v0.x);
            acc[2] += bf2f_lo(v0.y); acc[3] += bf2f_hi(v0.y);
            acc[4] += bf2f_lo(v0.z); acc[5] += bf2f_hi(v0.z);
            acc[6] += bf2f_lo(v0.w); acc[7] += bf2f_hi(v0.w);
        }
    }
    #pragma unroll
    for (int k = 0; k < 8; ++k) {                // fold octs
        acc[k] += __shfl_xor(acc[k], 8);
        acc[k] += __shfl_xor(acc[k], 16);
        acc[k] += __shfl_xor(acc[k], 32);
    }
    if (g == 0) {
        uint4 vs = *(const uint4*)(hp + (size_t)node * 64);   // scaled self
        float4 ba = *(const float4*)(bias + 8 * i);
        float4 bb = *(const float4*)(bias + 8 * i + 4);
        float4 r0, r1;
        r0.x = (acc[0] + bf2f_lo(vs.x)) * isd_i + ba.x;
        r0.y = (acc[1] + bf2f_hi(vs.x)) * isd_i + ba.y;
        r0.z = (acc[2] + bf2f_lo(vs.y)) * isd_i + ba.z;
        r0.w = (acc[3] + bf2f_hi(vs.y)) * isd_i + ba.w;
        r1.x = (acc[4] + bf2f_lo(vs.z)) * isd_i + bb.x;
        r1.y = (acc[5] + bf2f_hi(vs.z)) * isd_i + bb.y;
        r1.z = (acc[6] + bf2f_lo(vs.w)) * isd_i + bb.z;
        r1.w = (acc[7] + bf2f_hi(vs.w)) * isd_i + bb.w;
        float* op = out + (size_t)node * 64 + 8 * i;
        *(float4*)op = r0;
        *(float4*)(op + 4) = r1;
    }
}

static inline size_t align256(size_t x) { return (x + 255) & ~(size_t)255; }
static inline size_t maxsz(size_t a, size_t b) { return a > b ? a : b; }

extern "C" void kernel_launch(void* const* d_in, const int* in_sizes, int n_in,
                              void* d_out, int out_size, void* d_ws, size_t ws_size,
                              hipStream_t stream) {
    const float* x  = (const float*)d_in[0];
    const int*   ei = (const int*)d_in[1];
    const float* W1 = (const float*)d_in[2];
    const float* b1 = (const float*)d_in[3];
    const float* W2 = (const float*)d_in[4];
    const float* b2 = (const float*)d_in[5];
    float* out = (float*)d_out;

    const int N = in_sizes[0] / GCN_IN;   // 50000
    const int E = in_sizes[1] / 2;        // 800000
    const int* src = ei;
    const int* dst = ei + E;
    const int nb = (N + 127) >> 7;        // buckets (391)

    char* ws = (char*)d_ws;
    size_t o = 0;
    int*    cnt     = (int*)(ws + o);    o += align256((size_t)N * 4);
    int*    ovfcnt  = (int*)(ws + o);    // spillcnt lives 4B after ovfcnt
    int*    spillcnt = ovfcnt + 1;       o += 256;
    int2*   ovf     = (int2*)(ws + o);   o += align256((size_t)OVF_CAP * 8);
    uint*   spill   = (uint*)(ws + o);   o += align256((size_t)SPILL_CAP * 4);
    ushort* slot    = (ushort*)(ws + o); o += align256((size_t)N * CAP * 2);
    ushort* hb      = (ushort*)(ws + o); o += align256((size_t)N * GCN_H * 2);
    size_t seg_sz   = align256((size_t)nb * PASSA_BLOCKS * SEG_CAP * 4);
    size_t cntab_sz = align256((size_t)nb * PASSA_BLOCKS * 2);
    size_t h1_sz    = align256((size_t)N * GCN_H * 2);
    char*  zone     = ws + o;            o += maxsz(seg_sz + cntab_sz, h1_sz);
    uint*   seg    = (uint*)zone;
    ushort* cntAB  = (ushort*)(zone + seg_sz);
    ushort* h1b    = (ushort*)zone;
    ushort* h2b    = (ushort*)(ws + o);  o += align256((size_t)N * GCN_OUT * 2);

    // zero ovfcnt + spillcnt only (cnt written directly by passB)
    (void)hipMemsetAsync(ovfcnt, 0, 256, stream);

    // 1. fused: bucket-sort passA || MFMA GEMM1 -> hb (unscaled bf16)
    {
        int gemm_blocks = (N + 63) / 64;
        k_fused1<<<PASSA_BLOCKS + gemm_blocks, 256, 0, stream>>>(
            src, dst, seg, cntAB, spillcnt, spill, E, x, W1, hb, N, N);
    }

    // 1b. passB: per-bucket slot/cnt build, LDS-staged dense write-out
    k_passB<<<nb, 256, 0, stream>>>(seg, cntAB, spillcnt, spill, cnt, slot,
                                    ovfcnt, ovf, N);

    // 2. agg layer 1 -> h1b (once; 28us known)
    k_agg128<<<(N * 64 + 255) / 256, 256, 0, stream>>>(hb, cnt, slot, b1,
                                                       ovfcnt, ovf, h1b, N);

    // 3. MFMA GEMM2 x5 (pure, idempotent; 4 extra for measurement)
    for (int rep = 0; rep < 5; ++rep)
        k_gemm2<<<(N + 63) / 64, 256, 0, stream>>>(h1b, W2, cnt, h2b, N);

    // 4. agg layer 2 x5 (pure, idempotent; 4 extra for measurement)
    for (int rep = 0; rep < 5; ++rep)
        k_agg64<<<(N * 64 + 255) / 256, 256, 0, stream>>>(h2b, cnt, slot, b2,
                                                          ovfcnt, ovf, out, N);
}

// Round 9
// 170.721 us; speedup vs baseline: 1.7374x; 1.7374x over previous
//
#include <hip/hip_runtime.h>
#include <hip/hip_bf16.h>

// ---------------------------------------------------------------------------
// GCN 2-layer forward, round 21 — RESTORE BEST (r17 pipeline, 175.5us).
// The r18-r20 measurement rounds priced every component; ledger (us):
//   fixed(fill+restores+gaps) ~92 | buildchain ~28 | agg128 ~28 | g2+agg64 ~27
// All kernel components within ~15% of structural floors:
//   - agg128: 205MB random row-gather @ ~7.3 TB/s measured fabric service
//     (= the 28us; 800K edges x 256B mandatory, zero reuse in random graph).
//   - agg64: 102MB gather, same service rate.
//   - buildchain: 2-pass LDS sort + GEMM1 overlap, streams ~60MB.
// Refuted levers: atomic scope (r13), seg-store coalescing (r16), slot-store
// LDS staging (r17-delta: null), GEMM2-fusion into agg128 (r11), src-sorted
// CSR (r10). fp8 h fails absmax budget. Agg-then-GEMM orderings worse.
// Remaining theoretical gap ~13us = launch gaps + tails; no lever with
// expected value > noise identified. Next: ROOFLINE declaration.
// ---------------------------------------------------------------------------

#define GCN_IN   128
#define GCN_H    128
#define GCN_OUT  64
#define CAP      64
#define OVF_CAP  32768
#define SPILL_CAP 65536
#define PASSA_BLOCKS 256
#define SEG_CAP  24          // per-(bucket,block) capacity; Poisson(8) tail ~0
#define SORT_CAP 4096        // max edges per passA block (strided split)

using short8 = __attribute__((ext_vector_type(8))) short;   // 8 bf16, 4 VGPRs
using f32x4  = __attribute__((ext_vector_type(4))) float;   // MFMA acc
using int4v  = __attribute__((ext_vector_type(4))) int;     // native vec4 int

__device__ __forceinline__ ushort f2bf(float f) {     // fp32 -> bf16 RNE
    uint b = __float_as_uint(f);
    b = (b + 0x7FFFu + ((b >> 16) & 1u)) >> 16;
    return (ushort)b;
}
__device__ __forceinline__ float bf2f_lo(uint u) { return __uint_as_float(u << 16); }
__device__ __forceinline__ float bf2f_hi(uint u) { return __uint_as_float(u & 0xFFFF0000u); }

// ---------------- fused: [0,PASSA) bucket sort || [PASSA,..) MFMA GEMM1 -----
__global__ __launch_bounds__(256) void k_fused1(
        const int* __restrict__ src, const int* __restrict__ dst,
        uint* __restrict__ seg, ushort* __restrict__ cntAB,
        int* __restrict__ spillcnt, uint* __restrict__ spill, int E,
        const float* __restrict__ A, const float* __restrict__ B,
        ushort* __restrict__ C, int M, int N) {
    __shared__ __align__(16) uint smemU[5760];     // 23040 B union
    const int tid = threadIdx.x;
    const int nb  = (N + 127) >> 7;                // buckets (391 @ N=50000)

    if (blockIdx.x < PASSA_BLOCKS) {
        uint* histL  = smemU;                      // [512]
        uint* scanEx = smemU + 512;                // [512]
        uint* hist2  = smemU + 1024;               // [512]
        uint* sorted = smemU + 1536;               // [SORT_CAP]
        uint* totalS = smemU + 1536 + SORT_CAP;    // [1]

        const int blk = blockIdx.x;
        const int stride4 = PASSA_BLOCKS * 256 * 4;
        for (int i = tid; i < 512; i += 256) { histL[i] = 0; hist2[i] = 0; }
        __syncthreads();

        // phase 1: histogram of this block's edges over buckets
        for (int e = (blk * 256 + tid) * 4; e < E; e += stride4) {
            int4v d4 = __builtin_nontemporal_load((const int4v*)(dst + e));
            #pragma unroll
            for (int k = 0; k < 4; ++k) atomicAdd(&histL[d4[k] >> 7], 1u);
        }
        __syncthreads();

        // phase 2: single-wave exclusive scan over 512 buckets
        if (tid < 64) {
            int base = tid * 8;
            uint loc[8];
            uint run = 0;
            #pragma unroll
            for (int j = 0; j < 8; ++j) { loc[j] = run; run += histL[base + j]; }
            uint inc = run;
            #pragma unroll
            for (int d = 1; d < 64; d <<= 1) {
                uint v = __shfl_up(inc, d, 64);
                if (tid >= d) inc += v;
            }
            uint exc = inc - run;
            #pragma unroll
            for (int j = 0; j < 8; ++j) scanEx[base + j] = exc + loc[j];
            if (tid == 63) totalS[0] = inc;        // block's edge count
        }
        __syncthreads();

        // per-(bucket,block) counts for passB
        for (int b = tid; b < nb; b += 256)
            cntAB[(size_t)b * PASSA_BLOCKS + blk] =
                (ushort)min((int)histL[b], SEG_CAP);

        // phase 3: re-read edges (L2-hot), rank-scatter into LDS
        for (int e = (blk * 256 + tid) * 4; e < E; e += stride4) {
            int4v d4 = __builtin_nontemporal_load((const int4v*)(dst + e));
            int4v s4 = __builtin_nontemporal_load((const int4v*)(src + e));
            #pragma unroll
            for (int k = 0; k < 4; ++k) {
                int d = d4[k];
                int b = d >> 7;
                uint r = atomicAdd(&hist2[b], 1u);
                sorted[scanEx[b] + r] = ((uint)d << 16) | (uint)s4[k];
            }
        }
        __syncthreads();

        // phase 4: linear write-out; bucket runs are consecutive dwords
        const int myE = (int)totalS[0];
        for (int i = tid; i < myE; i += 256) {
            uint pr = sorted[i];
            int b = (int)(pr >> 23);               // d>>7
            int gpos = i - (int)scanEx[b];
            if (gpos < SEG_CAP) {
                seg[((size_t)b * PASSA_BLOCKS + blk) * SEG_CAP + gpos] = pr;
            } else {                               // ~0.1 expected, graph-fixed
                int q = atomicAdd(spillcnt, 1);
                if (q < SPILL_CAP) spill[q] = pr;
            }
        }
        return;
    }

    // ---- MFMA GEMM1: 64 rows x 128 cols per block, BK=32 chunks ----
    ushort (*As)[40] = (ushort (*)[40])(smemU);           // 64x40 bf16, 5120B
    ushort (*Bs)[40] = (ushort (*)[40])(smemU + 1280);    // 128x40 bf16, 10240B
    const int g    = blockIdx.x - PASSA_BLOCKS;
    const int row0 = g * 64;
    const int w    = tid >> 6;
    const int lane = tid & 63;
    const int l15  = lane & 15;
    const int q8   = (lane >> 4) * 8;

    f32x4 acc[8];
    #pragma unroll
    for (int t = 0; t < 8; ++t) {
        acc[t][0] = 0.f; acc[t][1] = 0.f; acc[t][2] = 0.f; acc[t][3] = 0.f;
    }
    for (int kb = 0; kb < 128; kb += 32) {
        #pragma unroll
        for (int tt = 0; tt < 2; ++tt) {
            int f = tid * 4 + tt * 1024;
            int r = f >> 5;
            int k = f & 31;
            float4 v = make_float4(0.f, 0.f, 0.f, 0.f);
            int gr = row0 + r;
            if (gr < M) v = *(const float4*)(A + (size_t)gr * 128 + kb + k);
            ushort4 o;
            o.x = f2bf(v.x); o.y = f2bf(v.y); o.z = f2bf(v.z); o.w = f2bf(v.w);
            *(ushort4*)&As[r][k] = o;
        }
        #pragma unroll
        for (int tt = 0; tt < 4; ++tt) {
            int f = tid * 4 + tt * 1024;
            int k = f >> 7;
            int n = f & 127;
            float4 v = *(const float4*)(B + (size_t)(kb + k) * 128 + n);
            Bs[n + 0][k] = f2bf(v.x);
            Bs[n + 1][k] = f2bf(v.y);
            Bs[n + 2][k] = f2bf(v.z);
            Bs[n + 3][k] = f2bf(v.w);
        }
        __syncthreads();
        short8 a = *(const short8*)&As[16 * w + l15][q8];
        #pragma unroll
        for (int t = 0; t < 8; ++t) {
            short8 b = *(const short8*)&Bs[16 * t + l15][q8];
            acc[t] = __builtin_amdgcn_mfma_f32_16x16x32_bf16(a, b, acc[t], 0, 0, 0);
        }
        __syncthreads();
    }
    const int quad = lane >> 4;
    #pragma unroll
    for (int r = 0; r < 4; ++r) {
        int grow = row0 + 16 * w + quad * 4 + r;
        if (grow < M) {
            #pragma unroll
            for (int t = 0; t < 8; ++t) {
                __builtin_nontemporal_store(
                    f2bf(acc[t][r]), C + (size_t)grow * 128 + 16 * t + l15);
            }
        }
    }
}

// ---------------- passB: per-bucket slot/cnt build, LDS-staged window -------
__global__ __launch_bounds__(256) void k_passB(const uint* __restrict__ seg,
                                               const ushort* __restrict__ cntAB,
                                               const int* __restrict__ spillcnt,
                                               const uint* __restrict__ spill,
                                               int* __restrict__ cnt,
                                               ushort* __restrict__ slot,
                                               int* __restrict__ ovfcnt,
                                               int2* __restrict__ ovf, int N) {
    __shared__ int cntL[128];
    __shared__ __align__(16) ushort slotL[128 * CAP];   // 16KB window
    const int tid  = threadIdx.x;
    const int b    = blockIdx.x;
    const int base = b << 7;
    if (tid < 128) cntL[tid] = 0;
    __syncthreads();

    const int cs = (int)cntAB[(size_t)b * PASSA_BLOCKS + tid];
    const uint* sp = seg + ((size_t)b * PASSA_BLOCKS + tid) * SEG_CAP;
    for (int c4 = 0; c4 < SEG_CAP; c4 += 4) {
        if (c4 >= cs) break;
        uint4 v = *(const uint4*)(sp + c4);            // 16B-aligned (96B seg)
        const uint* vv = (const uint*)&v;
        #pragma unroll
        for (int k = 0; k < 4; ++k) {
            int idx = c4 + k;
            if (idx < cs) {
                uint pr = vv[k];
                int d = (int)(pr >> 16);
                int s = (int)(pr & 0xFFFFu);
                int pos = atomicAdd(&cntL[d - base], 1);   // LDS
                if (pos < CAP) {
                    slotL[(d - base) * CAP + pos] = (ushort)s;
                } else {                                   // degree > 64: ~never
                    int q = atomicAdd(ovfcnt, 1);
                    if (q < OVF_CAP) ovf[q] = make_int2(d, s);
                }
            }
        }
    }
    // spill drain (expected 0-2 entries total across the whole graph)
    const int spn = min(*spillcnt, SPILL_CAP);
    for (int t = tid; t < spn; t += 256) {
        uint pr = spill[t];
        int d = (int)(pr >> 16);
        if (d >= base && d < base + 128) {
            int s = (int)(pr & 0xFFFFu);
            int pos = atomicAdd(&cntL[d - base], 1);
            if (pos < CAP) {
                slotL[(d - base) * CAP + pos] = (ushort)s;
            } else {
                int q = atomicAdd(ovfcnt, 1);
                if (q < OVF_CAP) ovf[q] = make_int2(d, s);
            }
        }
    }
    __syncthreads();
    // cnt: sole owner, write directly (no memset needed)
    if (tid < 128) {
        int d = base + tid;
        if (d < N) cnt[d] = cntL[tid];
    }
    // slot window: dense uint4 write-out (unwritten entries = LDS garbage,
    // same class as harness poison; agg masks beyond degm).
    ushort* swin = slot + (size_t)base * CAP;
    const uint4* sl4 = (const uint4*)slotL;
    #pragma unroll
    for (int t = 0; t < 4; ++t) {
        int i = tid + t * 256;                     // uint4 index, row = i>>3
        if (base + (i >> 3) < N) ((uint4*)swin)[i] = sl4[i];
    }
}

// ---------------- agg layer 1: F=128, unscaled bf16 in, bf16 out, relu ------
__global__ __launch_bounds__(256) void k_agg128(const ushort* __restrict__ h,
                                                const int* __restrict__ cnt,
                                                const ushort* __restrict__ slot,
                                                const float* __restrict__ bias,
                                                const int* __restrict__ ovfcnt,
                                                const int2* __restrict__ ovf,
                                                ushort* __restrict__ out, int n) {
    int node = (blockIdx.x * 256 + threadIdx.x) >> 6;
    int lane = threadIdx.x & 63;
    if (node >= n) return;
    int deg = cnt[node];
    int degm = min(deg, CAP);
    float isd_i = rsqrtf((float)(deg + 1));
    int sidx = (int)__builtin_nontemporal_load(slot + (size_t)node * CAP + lane);
    bool valid = lane < degm;
    if (!valid) sidx = 0;
    float wl = valid ? rsqrtf((float)(cnt[sidx] + 1)) : 0.f;

    const int q = lane >> 4;          // 0..3
    const int i = lane & 15;          // 0..15
    const ushort* hp = h + 8 * i;     // 8 bf16 feats per lane

    float acc[8] = {};
    for (int j = 0; j < degm; j += 8) {          // 8 edges/iter, 2 gathers
        int j0 = j + q;
        int j1 = j + 4 + q;
        int   s0 = __shfl(sidx, j0);
        int   s1 = __shfl(sidx, j1);
        float w0 = __shfl(wl, j0);               // 0 beyond degm
        float w1 = __shfl(wl, j1);
        uint4 v0 = *(const uint4*)(hp + (size_t)s0 * 128);
        uint4 v1 = *(const uint4*)(hp + (size_t)s1 * 128);
        acc[0] += w0 * bf2f_lo(v0.x) + w1 * bf2f_lo(v1.x);
        acc[1] += w0 * bf2f_hi(v0.x) + w1 * bf2f_hi(v1.x);
        acc[2] += w0 * bf2f_lo(v0.y) + w1 * bf2f_lo(v1.y);
        acc[3] += w0 * bf2f_hi(v0.y) + w1 * bf2f_hi(v1.y);
        acc[4] += w0 * bf2f_lo(v0.z) + w1 * bf2f_lo(v1.z);
        acc[5] += w0 * bf2f_hi(v0.z) + w1 * bf2f_hi(v1.z);
        acc[6] += w0 * bf2f_lo(v0.w) + w1 * bf2f_lo(v1.w);
        acc[7] += w0 * bf2f_hi(v0.w) + w1 * bf2f_hi(v1.w);
    }
    int ovn = *ovfcnt;                            // ~always 0
    for (int t = 0; t < ovn; ++t) {
        int2 p = ovf[t];
        if (p.x == node && q == 0) {
            float w0 = rsqrtf((float)(cnt[p.y] + 1));
            uint4 v0 = *(const uint4*)(hp + (size_t)p.y * 128);
            acc[0] += w0 * bf2f_lo(v0.x); acc[1] += w0 * bf2f_hi(v0.x);
            acc[2] += w0 * bf2f_lo(v0.y); acc[3] += w0 * bf2f_hi(v0.y);
            acc[4] += w0 * bf2f_lo(v0.z); acc[5] += w0 * bf2f_hi(v0.z);
            acc[6] += w0 * bf2f_lo(v0.w); acc[7] += w0 * bf2f_hi(v0.w);
        }
    }
    #pragma unroll
    for (int k = 0; k < 8; ++k) {                 // fold quads
        acc[k] += __shfl_xor(acc[k], 16);
        acc[k] += __shfl_xor(acc[k], 32);
    }
    if (q == 0) {
        uint4 vs = *(const uint4*)(hp + (size_t)node * 128);  // self (unscaled)
        float4 ba = *(const float4*)(bias + 8 * i);
        float4 bb = *(const float4*)(bias + 8 * i + 4);
        float r0 = fmaxf((acc[0] + isd_i * bf2f_lo(vs.x)) * isd_i + ba.x, 0.f);
        float r1 = fmaxf((acc[1] + isd_i * bf2f_hi(vs.x)) * isd_i + ba.y, 0.f);
        float r2 = fmaxf((acc[2] + isd_i * bf2f_lo(vs.y)) * isd_i + ba.z, 0.f);
        float r3 = fmaxf((acc[3] + isd_i * bf2f_hi(vs.y)) * isd_i + ba.w, 0.f);
        float r4 = fmaxf((acc[4] + isd_i * bf2f_lo(vs.z)) * isd_i + bb.x, 0.f);
        float r5 = fmaxf((acc[5] + isd_i * bf2f_hi(vs.z)) * isd_i + bb.y, 0.f);
        float r6 = fmaxf((acc[6] + isd_i * bf2f_lo(vs.w)) * isd_i + bb.z, 0.f);
        float r7 = fmaxf((acc[7] + isd_i * bf2f_hi(vs.w)) * isd_i + bb.w, 0.f);
        uint4 o;
        o.x = (uint)f2bf(r0) | ((uint)f2bf(r1) << 16);
        o.y = (uint)f2bf(r2) | ((uint)f2bf(r3) << 16);
        o.z = (uint)f2bf(r4) | ((uint)f2bf(r5) << 16);
        o.w = (uint)f2bf(r6) | ((uint)f2bf(r7) << 16);
        *(uint4*)(out + (size_t)node * 128 + 8 * i) = o;
    }
}

// ---------------- MFMA GEMM2: h2[N][64] bf16 (isd-scaled) = h1 @ W2 ---------
__global__ __launch_bounds__(256) void k_gemm2(const ushort* __restrict__ A,
                                               const float* __restrict__ B,
                                               const int* __restrict__ cnt,
                                               ushort* __restrict__ C, int M) {
    __shared__ __align__(16) ushort As[64][136];   // [m][k] bf16
    __shared__ __align__(16) ushort Bs[64][136];   // [n][k] bf16 (W2^T)
    const int tid  = threadIdx.x;
    const int w    = tid >> 6;
    const int lane = tid & 63;
    const int l15  = lane & 15;
    const int q8   = (lane >> 4) * 8;
    const int row0 = blockIdx.x * 64;

    #pragma unroll
    for (int t = 0; t < 4; ++t) {
        int f = tid * 8 + t * 2048;
        int r = f >> 7;
        int k = f & 127;
        uint4 v = make_uint4(0u, 0u, 0u, 0u);
        int gr = row0 + r;
        if (gr < M) v = *(const uint4*)(A + (size_t)gr * 128 + k);
        *(uint4*)&As[r][k] = v;
    }
    #pragma unroll
    for (int t = 0; t < 8; ++t) {
        int f = tid * 4 + t * 1024;
        int k = f >> 6;
        int n = f & 63;
        float4 v = *(const float4*)(B + (size_t)k * 64 + n);
        Bs[n + 0][k] = f2bf(v.x);
        Bs[n + 1][k] = f2bf(v.y);
        Bs[n + 2][k] = f2bf(v.z);
        Bs[n + 3][k] = f2bf(v.w);
    }
    __syncthreads();

    f32x4 acc[4];
    #pragma unroll
    for (int t = 0; t < 4; ++t) {
        acc[t][0] = 0.f; acc[t][1] = 0.f; acc[t][2] = 0.f; acc[t][3] = 0.f;
    }
    #pragma unroll
    for (int kt = 0; kt < 4; ++kt) {
        short8 a = *(const short8*)&As[16 * w + l15][32 * kt + q8];
        #pragma unroll
        for (int t = 0; t < 4; ++t) {
            short8 b = *(const short8*)&Bs[16 * t + l15][32 * kt + q8];
            acc[t] = __builtin_amdgcn_mfma_f32_16x16x32_bf16(a, b, acc[t], 0, 0, 0);
        }
    }
    const int quad = lane >> 4;
    #pragma unroll
    for (int r = 0; r < 4; ++r) {
        int grow = row0 + 16 * w + quad * 4 + r;
        if (grow < M) {
            float ws = rsqrtf((float)(cnt[grow] + 1));   // pre-scale by isd_src
            #pragma unroll
            for (int t = 0; t < 4; ++t) {
                C[(size_t)grow * 64 + 16 * t + l15] = f2bf(ws * acc[t][r]);
            }
        }
    }
}

// ---------------- agg layer 2: F=64, prescaled bf16 in, fp32 out ------------
__global__ __launch_bounds__(256) void k_agg64(const ushort* __restrict__ h,
                                               const int* __restrict__ cnt,
                                               const ushort* __restrict__ slot,
                                               const float* __restrict__ bias,
                                               const int* __restrict__ ovfcnt,
                                               const int2* __restrict__ ovf,
                                               float* __restrict__ out, int n) {
    int node = (blockIdx.x * 256 + threadIdx.x) >> 6;
    int lane = threadIdx.x & 63;
    if (node >= n) return;
    int deg = cnt[node];
    int degm = min(deg, CAP);
    float isd_i = rsqrtf((float)(deg + 1));
    int sidx = (int)__builtin_nontemporal_load(slot + (size_t)node * CAP + lane);

    const int g = lane >> 3;          // 0..7
    const int i = lane & 7;           // 0..7
    const ushort* hp = h + 8 * i;

    float acc[8] = {};
    for (int j = 0; j < degm; j += 16) {         // 16 edges/iter, 2 gathers
        int j0 = j + g;
        int j1 = j + 8 + g;
        int   s0 = __shfl(sidx, j0);
        int   s1 = __shfl(sidx, j1);
        float w0 = (j0 < degm) ? 1.f : 0.f;
        float w1 = (j1 < degm) ? 1.f : 0.f;
        uint4 v0 = *(const uint4*)(hp + (size_t)s0 * 64);
        uint4 v1 = *(const uint4*)(hp + (size_t)s1 * 64);
        acc[0] += w0 * bf2f_lo(v0.x) + w1 * bf2f_lo(v1.x);
        acc[1] += w0 * bf2f_hi(v0.x) + w1 * bf2f_hi(v1.x);
        acc[2] += w0 * bf2f_lo(v0.y) + w1 * bf2f_lo(v1.y);
        acc[3] += w0 * bf2f_hi(v0.y) + w1 * bf2f_hi(v1.y);
        acc[4] += w0 * bf2f_lo(v0.z) + w1 * bf2f_lo(v1.z);
        acc[5] += w0 * bf2f_hi(v0.z) + w1 * bf2f_hi(v1.z);
        acc[6] += w0 * bf2f_lo(v0.w) + w1 * bf2f_lo(v1.w);
        acc[7] += w0 * bf2f_hi(v0.w) + w1 * bf2f_hi(v1.w);
    }
    int ovn = *ovfcnt;
    for (int t = 0; t < ovn; ++t) {
        int2 p = ovf[t];
        if (p.x == node && g == 0) {             // h2 rows prescaled by isd_s
            uint4 v0 = *(const uint4*)(hp + (size_t)p.y * 64);
            acc[0] += bf2f_lo(v0.x); acc[1] += bf2f_hi(v0.x);
            acc[2] += bf2f_lo(v0.y); acc[3] += bf2f_hi(v0.y);
            acc[4] += bf2f_lo(v0.z); acc[5] += bf2f_hi(v0.z);
            acc[6] += bf2f_lo(v0.w); acc[7] += bf2f_hi(v0.w);
        }
    }
    #pragma unroll
    for (int k = 0; k < 8; ++k) {                // fold octs
        acc[k] += __shfl_xor(acc[k], 8);
        acc[k] += __shfl_xor(acc[k], 16);
        acc[k] += __shfl_xor(acc[k], 32);
    }
    if (g == 0) {
        uint4 vs = *(const uint4*)(hp + (size_t)node * 64);   // scaled self
        float4 ba = *(const float4*)(bias + 8 * i);
        float4 bb = *(const float4*)(bias + 8 * i + 4);
        float4 r0, r1;
        r0.x = (acc[0] + bf2f_lo(vs.x)) * isd_i + ba.x;
        r0.y = (acc[1] + bf2f_hi(vs.x)) * isd_i + ba.y;
        r0.z = (acc[2] + bf2f_lo(vs.y)) * isd_i + ba.z;
        r0.w = (acc[3] + bf2f_hi(vs.y)) * isd_i + ba.w;
        r1.x = (acc[4] + bf2f_lo(vs.z)) * isd_i + bb.x;
        r1.y = (acc[5] + bf2f_hi(vs.z)) * isd_i + bb.y;
        r1.z = (acc[6] + bf2f_lo(vs.w)) * isd_i + bb.z;
        r1.w = (acc[7] + bf2f_hi(vs.w)) * isd_i + bb.w;
        float* op = out + (size_t)node * 64 + 8 * i;
        *(float4*)op = r0;
        *(float4*)(op + 4) = r1;
    }
}

static inline size_t align256(size_t x) { return (x + 255) & ~(size_t)255; }
static inline size_t maxsz(size_t a, size_t b) { return a > b ? a : b; }

extern "C" void kernel_launch(void* const* d_in, const int* in_sizes, int n_in,
                              void* d_out, int out_size, void* d_ws, size_t ws_size,
                              hipStream_t stream) {
    const float* x  = (const float*)d_in[0];
    const int*   ei = (const int*)d_in[1];
    const float* W1 = (const float*)d_in[2];
    const float* b1 = (const float*)d_in[3];
    const float* W2 = (const float*)d_in[4];
    const float* b2 = (const float*)d_in[5];
    float* out = (float*)d_out;

    const int N = in_sizes[0] / GCN_IN;   // 50000
    const int E = in_sizes[1] / 2;        // 800000
    const int* src = ei;
    const int* dst = ei + E;
    const int nb = (N + 127) >> 7;        // buckets (391)

    char* ws = (char*)d_ws;
    size_t o = 0;
    int*    cnt     = (int*)(ws + o);    o += align256((size_t)N * 4);
    int*    ovfcnt  = (int*)(ws + o);    // spillcnt lives 4B after ovfcnt
    int*    spillcnt = ovfcnt + 1;       o += 256;
    int2*   ovf     = (int2*)(ws + o);   o += align256((size_t)OVF_CAP * 8);
    uint*   spill   = (uint*)(ws + o);   o += align256((size_t)SPILL_CAP * 4);
    ushort* slot    = (ushort*)(ws + o); o += align256((size_t)N * CAP * 2);
    ushort* hb      = (ushort*)(ws + o); o += align256((size_t)N * GCN_H * 2);
    size_t seg_sz   = align256((size_t)nb * PASSA_BLOCKS * SEG_CAP * 4);
    size_t cntab_sz = align256((size_t)nb * PASSA_BLOCKS * 2);
    size_t h1_sz    = align256((size_t)N * GCN_H * 2);
    char*  zone     = ws + o;            o += maxsz(seg_sz + cntab_sz, h1_sz);
    uint*   seg    = (uint*)zone;
    ushort* cntAB  = (ushort*)(zone + seg_sz);
    ushort* h1b    = (ushort*)zone;
    ushort* h2b    = (ushort*)(ws + o);  o += align256((size_t)N * GCN_OUT * 2);

    // zero ovfcnt + spillcnt only (cnt written directly by passB)
    (void)hipMemsetAsync(ovfcnt, 0, 256, stream);

    // 1. fused: bucket-sort passA || MFMA GEMM1 -> hb (unscaled bf16)
    {
        int gemm_blocks = (N + 63) / 64;
        k_fused1<<<PASSA_BLOCKS + gemm_blocks, 256, 0, stream>>>(
            src, dst, seg, cntAB, spillcnt, spill, E, x, W1, hb, N, N);
    }

    // 1b. passB: per-bucket slot/cnt build, LDS-staged dense write-out
    k_passB<<<nb, 256, 0, stream>>>(seg, cntAB, spillcnt, spill, cnt, slot,
                                    ovfcnt, ovf, N);

    // 2. agg layer 1 -> h1b (bf16, per-edge isd weights)
    k_agg128<<<(N * 64 + 255) / 256, 256, 0, stream>>>(hb, cnt, slot, b1,
                                                       ovfcnt, ovf, h1b, N);

    // 3. MFMA GEMM2: h1b @ W2 -> h2b (bf16, isd-scaled epilogue)
    k_gemm2<<<(N + 63) / 64, 256, 0, stream>>>(h1b, W2, cnt, h2b, N);

    // 4. agg layer 2 -> out (fp32)
    k_agg64<<<(N * 64 + 255) / 256, 256, 0, stream>>>(h2b, cnt, slot, b2,
                                                      ovfcnt, ovf, out, N);
}